// Round 12
// baseline (27.437 us; speedup 1.0000x reference)
//
#include <hip/hip_runtime.h>

// Problem constants (from reference setup_inputs)
#define B_ 64
#define H_ 376
#define W_ 1248
#define N_ 48                // boxes per batch
#define R_ 8                 // rows per chunk (divides 376 = 47*8)
#define GRID_V (H_ / R_)     // 47 row-chunks
#define CPB 4                // chunks (batches) per block
#define GRID_B (B_ / CPB)    // 16
#define NB (GRID_V * GRID_B) // 752 blocks
#define NWORDS (W_ / 32)     // 39 mask words per row
#define MWORDS (R_ * NWORDS) // 312 words per chunk
#define F4ROW (W_ / 4)       // 312 float4 per row
#define BLOCK_MAIN 320       // 5 waves
#define BLOCK_RED 256        // reduce kernel: 4 waves, single block

typedef float f32x4 __attribute__((ext_vector_type(4)));

// Soft barrier: orders LDS only (zero -> raster -> consume) without hipcc's
// s_waitcnt vmcnt(0) drain that __syncthreads() emits before s_barrier.
// Global loads stay in flight across it. Producer-side lgkmcnt(0) BEFORE
// s_barrier per ISA rule ("s_waitcnt first if data dep").
#define SOFT_BAR()                                                \
    do {                                                          \
        asm volatile("s_waitcnt lgkmcnt(0)" ::: "memory");        \
        __builtin_amdgcn_s_barrier();                             \
    } while (0)

// R12 = R11's prefetch head (box + chunk0 + chunk1 issued first) + SOFT
// barriers in the hot path, so the prefetch actually survives the barrier.
//
// Mechanism discovered via R9/R10/R11 A/B chain:
//   hipcc drains vmcnt(0) before every __syncthreads-lowered s_barrier, so
//   ISSUE-before-__syncthreads is a blocking load, not a prefetch. R11
//   (17 loads drained at barrier 1) = 27.34 vs R9 (8 drained) = 26.38.
//   SOFT_BAR drains only lgkmcnt -> loads stay outstanding through raster.
//
// Session ledger:
//   R9  (two-dispatch, nt):     PASS 26.38  <- best
//   R10 (plain loads):          PASS 27.19  -> nt kept
//   R11 (prefetch, hard bars):  PASS 27.34  -> drain mechanism identified
//   R0/R3/R6 single-kernel family retired (latent ticket race, R1-R8).
__global__ __launch_bounds__(BLOCK_MAIN) void balancer_partials(
    const float* __restrict__ loss,
    const float* __restrict__ boxes,     // [B, N, 4] = (u1, v1, u2, v2)
    double* __restrict__ ws_fg,          // [NB] unique slots
    double* __restrict__ ws_tot)         // [NB] unique slots
{
    const int vc = blockIdx.x;          // row-chunk
    const int bb = blockIdx.y;          // batch slot: handles bb + 16*c
    const int t  = threadIdx.x;
    const int v0 = vc * R_;

    __shared__ unsigned int mask_flat[CPB * MWORDS];   // 4*312 words = 5 KB
    __shared__ double sred[2 * (BLOCK_MAIN / 64)];

    const bool active = (t < F4ROW);
    const int w  = t >> 3;
    const int sh = (t & 7) * 4;
    double dfg = 0.0, dtot = 0.0;
    f32x4 x0[R_], x1[R_];

#define ISSUE(X, c)                                                              \
    if (active) {                                                                \
        const float* bp = loss + ((size_t)((bb + GRID_B * (c)) * H_ + v0)) * W_  \
                        + (size_t)t * 4;                                         \
        _Pragma("unroll")                                                        \
        for (int r = 0; r < R_; ++r)                                             \
            X[r] = __builtin_nontemporal_load(                                   \
                reinterpret_cast<const f32x4*>(bp + (size_t)r * W_));            \
    }

#define CONSUME(X, c)                                                            \
    if (active) {                                                                \
        float fg = 0.f, tt = 0.f;                                                \
        _Pragma("unroll")                                                        \
        for (int r = 0; r < R_; ++r) {                                           \
            const unsigned int bits =                                            \
                (mask_flat[(c) * MWORDS + r * NWORDS + w] >> sh) & 0xFu;         \
            const f32x4 xv = X[r];                                               \
            tt += (xv.x + xv.y) + (xv.z + xv.w);                                 \
            fg += ((bits & 1u) ? xv.x : 0.f) + ((bits & 2u) ? xv.y : 0.f)        \
                + ((bits & 4u) ? xv.z : 0.f) + ((bits & 8u) ? xv.w : 0.f);       \
        }                                                                        \
        dfg += (double)fg; dtot += (double)tt;                                   \
    }

    // --- Prologue: box float4 + BOTH chunk-0/chunk-1 streams issued before
    // any LDS work; with SOFT_BAR they stay in flight through the raster.
    const bool raster = (t < CPB * N_);
    float4 bx;
    int rc = 0;
    if (raster) {
        rc = t / N_;
        const int i = t - rc * N_;
        const int b = bb + GRID_B * rc;
        bx = *reinterpret_cast<const float4*>(
            boxes + ((size_t)b * N_ + (size_t)i) * 4);
    }
    ISSUE(x0, 0);
    ISSUE(x1, 1);

    // Zero the mask words (1248 words, threads 0..311 write 4 each).
    if (t < MWORDS) {
        #pragma unroll
        for (int k = 0; k < CPB; ++k) mask_flat[t + k * MWORDS] = 0u;
    }
    SOFT_BAR();                       // LDS zero visible; loads NOT drained

    // Inverted raster: one thread per (chunk, box); ~6 LDS atomicOr/thread.
    if (raster) {
        int iu1 = (int)floorf(bx.x);
        int iv1 = (int)floorf(bx.y);
        int iu2 = (int)ceilf(bx.z);
        int iv2 = (int)ceilf(bx.w);
        int r1 = iv1 - v0; r1 = r1 < 0 ? 0 : r1;
        int r2 = iv2 - v0; r2 = r2 > R_ ? R_ : r2;
        iu1 = iu1 < 0 ? 0 : iu1;
        iu2 = iu2 > W_ ? W_ : iu2;
        if (r2 > r1 && iu2 > iu1) {
            const int w1 = iu1 >> 5;
            const int w2 = (iu2 + 31) >> 5;   // exclusive
            for (int ww = w1; ww < w2; ++ww) {
                const int lo = iu1 - (ww << 5);
                const int hi = iu2 - (ww << 5);
                const int l = lo < 0 ? 0 : lo;
                const int h = hi > 32 ? 32 : hi;
                const unsigned int mh = (h == 32) ? 0xFFFFFFFFu : ((1u << h) - 1u);
                const unsigned int m  = mh & ~((1u << l) - 1u);
                for (int r = r1; r < r2; ++r)
                    atomicOr(&mask_flat[rc * MWORDS + r * NWORDS + ww], m);
            }
        }
    }
    SOFT_BAR();                       // raster atomics visible; loads in flight

    // Consume ladder (chunks 0,1 outstanding since the prologue).
    CONSUME(x0, 0); ISSUE(x0, 2);
    CONSUME(x1, 1); ISSUE(x1, 3);
    CONSUME(x0, 2);
    CONSUME(x1, 3);

    // Block reduction in fp64 (5 waves of 64). Cold path: plain barriers.
    #pragma unroll
    for (int off = 32; off > 0; off >>= 1) {
        dfg  += __shfl_down(dfg,  off, 64);
        dtot += __shfl_down(dtot, off, 64);
    }
    const int wave = t >> 6;
    const int lane = t & 63;
    if (lane == 0) { sred[wave] = dfg; sred[(BLOCK_MAIN / 64) + wave] = dtot; }
    __syncthreads();
    if (t == 0) {
        double f = 0.0, s = 0.0;
        #pragma unroll
        for (int i = 0; i < BLOCK_MAIN / 64; ++i) {
            f += sred[i]; s += sred[(BLOCK_MAIN / 64) + i];
        }
        const int bid = bb * GRID_V + vc;
        // Plain unique-slot stores; visibility to the next dispatch is
        // guaranteed by the stream-order kernel boundary.
        ws_fg[bid]  = f;
        ws_tot[bid] = s;
    }
#undef ISSUE
#undef CONSUME
}

// Kernel 2: single block reduces the 752 slot-pairs and writes the 3 outputs.
__global__ __launch_bounds__(BLOCK_RED) void balancer_reduce(
    const double* __restrict__ ws_fg,
    const double* __restrict__ ws_tot,
    float* __restrict__ out)
{
    const int t = threadIdx.x;
    __shared__ double sred[2 * (BLOCK_RED / 64)];

    double fgA = 0.0, totA = 0.0;
    for (int i = t; i < NB; i += BLOCK_RED) {
        fgA  += ws_fg[i];
        totA += ws_tot[i];
    }
    #pragma unroll
    for (int off = 32; off > 0; off >>= 1) {
        fgA  += __shfl_down(fgA,  off, 64);
        totA += __shfl_down(totA, off, 64);
    }
    const int wave = t >> 6;
    const int lane = t & 63;
    if (lane == 0) { sred[wave] = fgA; sred[(BLOCK_RED / 64) + wave] = totA; }
    __syncthreads();
    if (t == 0) {
        double f = 0.0, s = 0.0;
        #pragma unroll
        for (int i = 0; i < BLOCK_RED / 64; ++i) {
            f += sred[i]; s += sred[(BLOCK_RED / 64) + i];
        }
        const double num = (double)B_ * (double)H_ * (double)W_;
        const double fg_loss = 13.0 * f / num;
        const double bg_loss = (s - f) / num;
        out[0] = (float)(fg_loss + bg_loss);
        out[1] = (float)fg_loss;
        out[2] = (float)bg_loss;
    }
}

extern "C" void kernel_launch(void* const* d_in, const int* in_sizes, int n_in,
                              void* d_out, int out_size, void* d_ws, size_t ws_size,
                              hipStream_t stream) {
    const float* loss  = (const float*)d_in[0];   // [B, H, W] fp32
    const float* boxes = (const float*)d_in[1];   // [B, N, 4] fp32
    float* out = (float*)d_out;                   // 3 fp32

    double* ws_fg  = (double*)d_ws;                        // NB doubles
    double* ws_tot = ws_fg + NB;                           // NB doubles

    // Two stream-ordered dispatches; no memset (all slots rewritten each call).
    dim3 grid(GRID_V, GRID_B, 1);
    balancer_partials<<<grid, BLOCK_MAIN, 0, stream>>>(loss, boxes, ws_fg, ws_tot);
    balancer_reduce<<<dim3(1, 1, 1), BLOCK_RED, 0, stream>>>(ws_fg, ws_tot, out);
}

// Round 14
// 26.912 us; speedup vs baseline: 1.0195x; 1.0195x over previous
//
#include <hip/hip_runtime.h>

// Problem constants (from reference setup_inputs)
#define B_ 64
#define H_ 376
#define W_ 1248
#define N_ 48                // boxes per batch
#define R_ 8                 // rows per chunk (divides 376 = 47*8)
#define GRID_V (H_ / R_)     // 47 row-chunks
#define CPB 2                // chunks (batches) per block  [R14: 4 -> 2]
#define GRID_B (B_ / CPB)    // 32
#define NB (GRID_V * GRID_B) // 1504 blocks -> 29.4 waves/CU co-resident
#define NWORDS (W_ / 32)     // 39 mask words per row
#define MWORDS (R_ * NWORDS) // 312 words per chunk
#define F4ROW (W_ / 4)       // 312 float4 per row
#define BLOCK_MAIN 320       // 5 waves
#define BLOCK_RED 256        // reduce kernel: 4 waves, single block

typedef float f32x4 __attribute__((ext_vector_type(4)));

// R14 = R9's proven two-dispatch structure with ONE parameter change:
// CPB 4 -> 2 (grid 752 -> 1504 blocks; 14.7 -> 29.4 waves/CU). Tests
// whether occupancy limits the stream rate (~5.5 vs 6.29 TB/s copy
// ceiling). Same total work; per-unit instruction shape is R9's exact
// pattern; NO sync-protocol change (dispatch boundary only — the one
// cross-block ordering mechanism proven in this harness).
//
// Session ledger:
//   R9  (two-dispatch, nt, CPB=4):  PASS 26.38  <- base/best
//   R10 (plain loads):              PASS 27.19  -> nt kept
//   R11/R12 (head prefetch):        PASS 27.34/27.44 -> head closed
//   R13 (cooperative grid sync):    FAIL (launch likely never ran) -> closed
//   R0/R3/R6 single-kernel ticket family: retired (latent race, R1-R8)
__global__ __launch_bounds__(BLOCK_MAIN) void balancer_partials(
    const float* __restrict__ loss,
    const float* __restrict__ boxes,     // [B, N, 4] = (u1, v1, u2, v2)
    double* __restrict__ ws_fg,          // [NB] unique slots
    double* __restrict__ ws_tot)         // [NB] unique slots
{
    const int vc = blockIdx.x;          // row-chunk
    const int bb = blockIdx.y;          // batch slot: handles bb + GRID_B*c
    const int t  = threadIdx.x;
    const int v0 = vc * R_;

    __shared__ unsigned int mask_flat[CPB * MWORDS];   // 2*312 words = 2.5 KB
    __shared__ double sred[2 * (BLOCK_MAIN / 64)];

    const bool active = (t < F4ROW);
    const int w  = t >> 3;
    const int sh = (t & 7) * 4;
    double dfg = 0.0, dtot = 0.0;
    f32x4 x0[R_], x1[R_];

#define ISSUE(X, c)                                                              \
    if (active) {                                                                \
        const float* bp = loss + ((size_t)((bb + GRID_B * (c)) * H_ + v0)) * W_  \
                        + (size_t)t * 4;                                         \
        _Pragma("unroll")                                                        \
        for (int r = 0; r < R_; ++r)                                             \
            X[r] = __builtin_nontemporal_load(                                   \
                reinterpret_cast<const f32x4*>(bp + (size_t)r * W_));            \
    }

#define CONSUME(X, c)                                                            \
    if (active) {                                                                \
        float fg = 0.f, tt = 0.f;                                                \
        _Pragma("unroll")                                                        \
        for (int r = 0; r < R_; ++r) {                                           \
            const unsigned int bits =                                            \
                (mask_flat[(c) * MWORDS + r * NWORDS + w] >> sh) & 0xFu;         \
            const f32x4 xv = X[r];                                               \
            tt += (xv.x + xv.y) + (xv.z + xv.w);                                 \
            fg += ((bits & 1u) ? xv.x : 0.f) + ((bits & 2u) ? xv.y : 0.f)        \
                + ((bits & 4u) ? xv.z : 0.f) + ((bits & 8u) ? xv.w : 0.f);       \
        }                                                                        \
        dfg += (double)fg; dtot += (double)tt;                                   \
    }

    // Chunk-0 loads in flight before any raster work (R9-proven head).
    ISSUE(x0, 0);

    // Zero the mask words (624 words, threads 0..311 write 2 each).
    if (t < MWORDS) {
        #pragma unroll
        for (int k = 0; k < CPB; ++k) mask_flat[t + k * MWORDS] = 0u;
    }
    __syncthreads();

    // Inverted raster: one thread per (chunk, box); ~6 LDS atomicOr/thread.
    if (t < CPB * N_) {
        const int c = t / N_;
        const int i = t - c * N_;
        const int b = bb + GRID_B * c;
        const float4 bx = *reinterpret_cast<const float4*>(
            boxes + ((size_t)b * N_ + (size_t)i) * 4);
        int iu1 = (int)floorf(bx.x);
        int iv1 = (int)floorf(bx.y);
        int iu2 = (int)ceilf(bx.z);
        int iv2 = (int)ceilf(bx.w);
        int r1 = iv1 - v0; r1 = r1 < 0 ? 0 : r1;
        int r2 = iv2 - v0; r2 = r2 > R_ ? R_ : r2;
        iu1 = iu1 < 0 ? 0 : iu1;
        iu2 = iu2 > W_ ? W_ : iu2;
        if (r2 > r1 && iu2 > iu1) {
            const int w1 = iu1 >> 5;
            const int w2 = (iu2 + 31) >> 5;   // exclusive
            for (int ww = w1; ww < w2; ++ww) {
                const int lo = iu1 - (ww << 5);
                const int hi = iu2 - (ww << 5);
                const int l = lo < 0 ? 0 : lo;
                const int h = hi > 32 ? 32 : hi;
                const unsigned int mh = (h == 32) ? 0xFFFFFFFFu : ((1u << h) - 1u);
                const unsigned int m  = mh & ~((1u << l) - 1u);
                for (int r = r1; r < r2; ++r)
                    atomicOr(&mask_flat[c * MWORDS + r * NWORDS + ww], m);
            }
        }
    }
    __syncthreads();

    // 2-chunk stream with register double-buffering (R9-proven pattern).
    ISSUE(x1, 1); CONSUME(x0, 0);
    CONSUME(x1, 1);

    // Block reduction in fp64 (5 waves of 64).
    #pragma unroll
    for (int off = 32; off > 0; off >>= 1) {
        dfg  += __shfl_down(dfg,  off, 64);
        dtot += __shfl_down(dtot, off, 64);
    }
    const int wave = t >> 6;
    const int lane = t & 63;
    if (lane == 0) { sred[wave] = dfg; sred[(BLOCK_MAIN / 64) + wave] = dtot; }
    __syncthreads();
    if (t == 0) {
        double f = 0.0, s = 0.0;
        #pragma unroll
        for (int i = 0; i < BLOCK_MAIN / 64; ++i) {
            f += sred[i]; s += sred[(BLOCK_MAIN / 64) + i];
        }
        const int bid = bb * GRID_V + vc;
        // Plain unique-slot stores; visibility to the next dispatch is
        // guaranteed by the stream-order kernel boundary.
        ws_fg[bid]  = f;
        ws_tot[bid] = s;
    }
#undef ISSUE
#undef CONSUME
}

// Kernel 2: single block reduces the 1504 slot-pairs and writes the outputs.
__global__ __launch_bounds__(BLOCK_RED) void balancer_reduce(
    const double* __restrict__ ws_fg,
    const double* __restrict__ ws_tot,
    float* __restrict__ out)
{
    const int t = threadIdx.x;
    __shared__ double sred[2 * (BLOCK_RED / 64)];

    double fgA = 0.0, totA = 0.0;
    for (int i = t; i < NB; i += BLOCK_RED) {
        fgA  += ws_fg[i];
        totA += ws_tot[i];
    }
    #pragma unroll
    for (int off = 32; off > 0; off >>= 1) {
        fgA  += __shfl_down(fgA,  off, 64);
        totA += __shfl_down(totA, off, 64);
    }
    const int wave = t >> 6;
    const int lane = t & 63;
    if (lane == 0) { sred[wave] = fgA; sred[(BLOCK_RED / 64) + wave] = totA; }
    __syncthreads();
    if (t == 0) {
        double f = 0.0, s = 0.0;
        #pragma unroll
        for (int i = 0; i < BLOCK_RED / 64; ++i) {
            f += sred[i]; s += sred[(BLOCK_RED / 64) + i];
        }
        const double num = (double)B_ * (double)H_ * (double)W_;
        const double fg_loss = 13.0 * f / num;
        const double bg_loss = (s - f) / num;
        out[0] = (float)(fg_loss + bg_loss);
        out[1] = (float)fg_loss;
        out[2] = (float)bg_loss;
    }
}

extern "C" void kernel_launch(void* const* d_in, const int* in_sizes, int n_in,
                              void* d_out, int out_size, void* d_ws, size_t ws_size,
                              hipStream_t stream) {
    const float* loss  = (const float*)d_in[0];   // [B, H, W] fp32
    const float* boxes = (const float*)d_in[1];   // [B, N, 4] fp32
    float* out = (float*)d_out;                   // 3 fp32

    double* ws_fg  = (double*)d_ws;                        // NB doubles
    double* ws_tot = ws_fg + NB;                           // NB doubles

    // Two stream-ordered dispatches; no memset (all slots rewritten each call).
    dim3 grid(GRID_V, GRID_B, 1);
    balancer_partials<<<grid, BLOCK_MAIN, 0, stream>>>(loss, boxes, ws_fg, ws_tot);
    balancer_reduce<<<dim3(1, 1, 1), BLOCK_RED, 0, stream>>>(ws_fg, ws_tot, out);
}

// Round 15
// 24.723 us; speedup vs baseline: 1.1098x; 1.0885x over previous
//
#include <hip/hip_runtime.h>

// Problem constants (from reference setup_inputs)
#define B_ 64
#define H_ 376
#define W_ 1248
#define N_ 48                // boxes per batch
#define R_ 8                 // rows per chunk (divides 376 = 47*8)
#define GRID_V (H_ / R_)     // 47 row-chunks
#define CPB 4                // chunks (batches) per block
#define GRID_B (B_ / CPB)    // 16
#define NB (GRID_V * GRID_B) // 752 blocks
#define NWORDS (W_ / 32)     // 39 mask words per row
#define MWORDS (R_ * NWORDS) // 312 words per chunk
#define F4ROW (W_ / 4)       // 312 float4 per row
#define BLOCK_MAIN 320       // 5 waves
#define BLOCK_RED 256        // reduce kernel: 4 waves, single block

typedef float f32x4 __attribute__((ext_vector_type(4)));

// R15 = R9-exact + ONE isolated change: the box float4 is loaded in the
// prologue (latency hides under zero+barrier) instead of serially between
// the two barriers. R11/R12 never isolated this — they bundled it with the
// x1-hoist (VGPR-pressure regression). +4 VGPRs only.
//
// Session ledger:
//   R9  (two-dispatch, nt, CPB=4):  PASS 26.38  <- base/best
//   R10 (plain loads):              PASS 27.19  -> nt kept
//   R11/R12 (box+x1 prefetch):      PASS 27.34/27.44 -> x1-hoist closed
//   R13 (cooperative):              FAIL -> closed
//   R14 (CPB=2, 2x occupancy):      PASS 26.91 -> occupancy closed
//   R0-R8 single-kernel ticket family: retired (latent race)
__global__ __launch_bounds__(BLOCK_MAIN) void balancer_partials(
    const float* __restrict__ loss,
    const float* __restrict__ boxes,     // [B, N, 4] = (u1, v1, u2, v2)
    double* __restrict__ ws_fg,          // [NB] unique slots
    double* __restrict__ ws_tot)         // [NB] unique slots
{
    const int vc = blockIdx.x;          // row-chunk
    const int bb = blockIdx.y;          // batch slot: handles bb + 16*c
    const int t  = threadIdx.x;
    const int v0 = vc * R_;

    __shared__ unsigned int mask_flat[CPB * MWORDS];   // 4*312 words = 5 KB
    __shared__ double sred[2 * (BLOCK_MAIN / 64)];

    const bool active = (t < F4ROW);
    const int w  = t >> 3;
    const int sh = (t & 7) * 4;
    double dfg = 0.0, dtot = 0.0;
    f32x4 x0[R_], x1[R_];

#define ISSUE(X, c)                                                              \
    if (active) {                                                                \
        const float* bp = loss + ((size_t)((bb + GRID_B * (c)) * H_ + v0)) * W_  \
                        + (size_t)t * 4;                                         \
        _Pragma("unroll")                                                        \
        for (int r = 0; r < R_; ++r)                                             \
            X[r] = __builtin_nontemporal_load(                                   \
                reinterpret_cast<const f32x4*>(bp + (size_t)r * W_));            \
    }

#define CONSUME(X, c)                                                            \
    if (active) {                                                                \
        float fg = 0.f, tt = 0.f;                                                \
        _Pragma("unroll")                                                        \
        for (int r = 0; r < R_; ++r) {                                           \
            const unsigned int bits =                                            \
                (mask_flat[(c) * MWORDS + r * NWORDS + w] >> sh) & 0xFu;         \
            const f32x4 xv = X[r];                                               \
            tt += (xv.x + xv.y) + (xv.z + xv.w);                                 \
            fg += ((bits & 1u) ? xv.x : 0.f) + ((bits & 2u) ? xv.y : 0.f)        \
                + ((bits & 4u) ? xv.z : 0.f) + ((bits & 8u) ? xv.w : 0.f);       \
        }                                                                        \
        dfg += (double)fg; dtot += (double)tt;                                   \
    }

    // --- Prologue: box float4 first (its ~200-900cy latency hides under the
    // zero+barrier), then chunk-0 loads (R9-proven). NO x1 hoist (R11/R12).
    const bool raster = (t < CPB * N_);
    float4 bx;
    int rc = 0;
    if (raster) {
        rc = t / N_;
        const int i = t - rc * N_;
        const int b = bb + GRID_B * rc;
        bx = *reinterpret_cast<const float4*>(
            boxes + ((size_t)b * N_ + (size_t)i) * 4);
    }
    ISSUE(x0, 0);

    // Zero the mask words (1248 words, threads 0..311 write 4 each).
    if (t < MWORDS) {
        #pragma unroll
        for (int k = 0; k < CPB; ++k) mask_flat[t + k * MWORDS] = 0u;
    }
    __syncthreads();

    // Inverted raster: one thread per (chunk, box); box already in registers.
    if (raster) {
        int iu1 = (int)floorf(bx.x);
        int iv1 = (int)floorf(bx.y);
        int iu2 = (int)ceilf(bx.z);
        int iv2 = (int)ceilf(bx.w);
        int r1 = iv1 - v0; r1 = r1 < 0 ? 0 : r1;
        int r2 = iv2 - v0; r2 = r2 > R_ ? R_ : r2;
        iu1 = iu1 < 0 ? 0 : iu1;
        iu2 = iu2 > W_ ? W_ : iu2;
        if (r2 > r1 && iu2 > iu1) {
            const int w1 = iu1 >> 5;
            const int w2 = (iu2 + 31) >> 5;   // exclusive
            for (int ww = w1; ww < w2; ++ww) {
                const int lo = iu1 - (ww << 5);
                const int hi = iu2 - (ww << 5);
                const int l = lo < 0 ? 0 : lo;
                const int h = hi > 32 ? 32 : hi;
                const unsigned int mh = (h == 32) ? 0xFFFFFFFFu : ((1u << h) - 1u);
                const unsigned int m  = mh & ~((1u << l) - 1u);
                for (int r = r1; r < r2; ++r)
                    atomicOr(&mask_flat[rc * MWORDS + r * NWORDS + ww], m);
            }
        }
    }
    __syncthreads();

    // Barrier-free 4-chunk stream with register double-buffering (R9-proven).
    ISSUE(x1, 1); CONSUME(x0, 0);
    ISSUE(x0, 2); CONSUME(x1, 1);
    ISSUE(x1, 3); CONSUME(x0, 2);
    CONSUME(x1, 3);

    // Block reduction in fp64 (5 waves of 64).
    #pragma unroll
    for (int off = 32; off > 0; off >>= 1) {
        dfg  += __shfl_down(dfg,  off, 64);
        dtot += __shfl_down(dtot, off, 64);
    }
    const int wave = t >> 6;
    const int lane = t & 63;
    if (lane == 0) { sred[wave] = dfg; sred[(BLOCK_MAIN / 64) + wave] = dtot; }
    __syncthreads();
    if (t == 0) {
        double f = 0.0, s = 0.0;
        #pragma unroll
        for (int i = 0; i < BLOCK_MAIN / 64; ++i) {
            f += sred[i]; s += sred[(BLOCK_MAIN / 64) + i];
        }
        const int bid = bb * GRID_V + vc;
        // Plain unique-slot stores; visibility to the next dispatch is
        // guaranteed by the stream-order kernel boundary.
        ws_fg[bid]  = f;
        ws_tot[bid] = s;
    }
#undef ISSUE
#undef CONSUME
}

// Kernel 2: single block reduces the 752 slot-pairs and writes the 3 outputs.
__global__ __launch_bounds__(BLOCK_RED) void balancer_reduce(
    const double* __restrict__ ws_fg,
    const double* __restrict__ ws_tot,
    float* __restrict__ out)
{
    const int t = threadIdx.x;
    __shared__ double sred[2 * (BLOCK_RED / 64)];

    double fgA = 0.0, totA = 0.0;
    for (int i = t; i < NB; i += BLOCK_RED) {
        fgA  += ws_fg[i];
        totA += ws_tot[i];
    }
    #pragma unroll
    for (int off = 32; off > 0; off >>= 1) {
        fgA  += __shfl_down(fgA,  off, 64);
        totA += __shfl_down(totA, off, 64);
    }
    const int wave = t >> 6;
    const int lane = t & 63;
    if (lane == 0) { sred[wave] = fgA; sred[(BLOCK_RED / 64) + wave] = totA; }
    __syncthreads();
    if (t == 0) {
        double f = 0.0, s = 0.0;
        #pragma unroll
        for (int i = 0; i < BLOCK_RED / 64; ++i) {
            f += sred[i]; s += sred[(BLOCK_RED / 64) + i];
        }
        const double num = (double)B_ * (double)H_ * (double)W_;
        const double fg_loss = 13.0 * f / num;
        const double bg_loss = (s - f) / num;
        out[0] = (float)(fg_loss + bg_loss);
        out[1] = (float)fg_loss;
        out[2] = (float)bg_loss;
    }
}

extern "C" void kernel_launch(void* const* d_in, const int* in_sizes, int n_in,
                              void* d_out, int out_size, void* d_ws, size_t ws_size,
                              hipStream_t stream) {
    const float* loss  = (const float*)d_in[0];   // [B, H, W] fp32
    const float* boxes = (const float*)d_in[1];   // [B, N, 4] fp32
    float* out = (float*)d_out;                   // 3 fp32

    double* ws_fg  = (double*)d_ws;                        // NB doubles
    double* ws_tot = ws_fg + NB;                           // NB doubles

    // Two stream-ordered dispatches; no memset (all slots rewritten each call).
    dim3 grid(GRID_V, GRID_B, 1);
    balancer_partials<<<grid, BLOCK_MAIN, 0, stream>>>(loss, boxes, ws_fg, ws_tot);
    balancer_reduce<<<dim3(1, 1, 1), BLOCK_RED, 0, stream>>>(ws_fg, ws_tot, out);
}